// Round 10
// baseline (80.271 us; speedup 1.0000x reference)
//
#include <hip/hip_runtime.h>
#include <hip/hip_bf16.h>

#define FEPS 1e-5f

constexpr int Bn = 4, Hn = 16, Sn = 4096, Dn = 64;
constexpr int NHEAD = Bn * Hn;          // 64 heads
constexpr int SLOT = Dn * Dn + Dn;      // 4160 floats: kv then ksum

typedef short short8 __attribute__((ext_vector_type(8)));
typedef float f32x4 __attribute__((ext_vector_type(4)));

__device__ __forceinline__ short f2bf(float f) {
    __hip_bfloat16 h = __float2bfloat16(f);
    return __builtin_bit_cast(short, h);
}

__device__ __forceinline__ float elem4(const float4& v, int i) {
    // i is compile-time constant under full unroll
    return i == 0 ? v.x : i == 1 ? v.y : i == 2 ? v.z : v.w;
}

// ---------------- Pass 1 (MFMA, coalesced): partial kv = K^T V and ksum ----------------
// Column-permuted fragment assignment: MFMA tile mt owns d-columns {4c+mt},
// so ONE float4 load K[s_j][4c] supplies slot j of ALL FOUR mt fragments
// (element mt). Same for V/nt. A and B use the same (lane,j)->s map, so the
// MFMA k-pairing is correct under any internal k layout (validated R9).
// Loads: 8 float4 per operand per 32-row slice, fully coalesced, no LDS in
// the main loop. Output index: d = 4*m_loc+mt, e = 4*n_loc+nt (epilogue).
// C/D layout (HW-verified m89): n_loc = lane&15, m_loc = (lane>>4)*4 + reg.
__global__ __launch_bounds__(256, 2) void pass1(const float* __restrict__ K,
                                                const float* __restrict__ V,
                                                float* __restrict__ part,
                                                int ch_s) {
    __shared__ float red[2048];   // 64 x 32 e-half reduction buffer
    __shared__ float ksr[256];    // per-wave ksum partials

    const int head = blockIdx.x;
    const int chunk = blockIdx.y;
    const int t = threadIdx.x;
    const int w = t >> 6;                  // wave 0..3
    const int l = t & 63;
    const int q16 = l >> 4;                // lane group 0..3
    const int lc = l & 15;                 // lane col 0..15
    const int wave_s = ch_s >> 2;          // s-rows per wave
    const int nsl = wave_s >> 5;           // 32-row slices per wave

    const size_t hbase = (size_t)head * Sn * Dn;
    const size_t s0w = (size_t)chunk * ch_s + (size_t)w * wave_s;
    // lane float4 base: row = s0w + q16*8 (+j, +32*sl), float4-col = lc
    const float4* Kp4 = (const float4*)(K + hbase + (s0w + q16 * 8) * Dn) + lc;
    const float4* Vp4 = (const float4*)(V + hbase + (s0w + q16 * 8) * Dn) + lc;

    f32x4 acc[4][4] = {};                  // [mt][nt]; true d=4*m_loc+mt, e=4*n_loc+nt
    float ks[4] = {0.f, 0.f, 0.f, 0.f};    // fp32 ksum partial for col 4*lc+mt

    for (int sl = 0; sl < nsl; ++sl) {
        float4 kr[8], vr[8];
        #pragma unroll
        for (int j = 0; j < 8; ++j) {
            kr[j] = Kp4[(sl * 32 + j) * 16];
            vr[j] = Vp4[(sl * 32 + j) * 16];
        }
        short8 af[4], bfr[4];
        #pragma unroll
        for (int mt = 0; mt < 4; ++mt) {
            short8 a, b;
            #pragma unroll
            for (int j = 0; j < 8; ++j) {
                float kf = elem4(kr[j], mt);
                float vf = elem4(vr[j], mt);
                a[j] = f2bf(kf);
                ks[mt] += kf;
                b[j] = f2bf(vf);
            }
            af[mt] = a;
            bfr[mt] = b;
        }
        #pragma unroll
        for (int mt = 0; mt < 4; ++mt)
            #pragma unroll
            for (int nt = 0; nt < 4; ++nt)
                acc[mt][nt] = __builtin_amdgcn_mfma_f32_16x16x32_bf16(
                    af[mt], bfr[nt], acc[mt][nt], 0, 0, 0);
    }

    // ksum: lane covers only its q16-group's s-rows -> reduce across groups
    #pragma unroll
    for (int mt = 0; mt < 4; ++mt) {
        ks[mt] += __shfl_xor(ks[mt], 16);
        ks[mt] += __shfl_xor(ks[mt], 32);
    }
    if (l < 16) {                          // lane l holds column 4*l+mt
        #pragma unroll
        for (int mt = 0; mt < 4; ++mt) ksr[w * Dn + 4 * l + mt] = ks[mt];
    }

    // ---- epilogue: reduce 4 wave partials in two 64x32 e-halves ----
    float* slot = part + ((size_t)chunk * NHEAD + head) * SLOT;
    const int ehalf = lc >> 3;             // e = 4*lc+nt -> half = lc>>3
    const int ebase = 4 * (lc & 7);        // e offset within half (+nt)
    #pragma unroll
    for (int h = 0; h < 2; ++h) {
        #pragma unroll
        for (int ww = 0; ww < 4; ++ww) {
            __syncthreads();
            if (w == ww && ehalf == h) {
                #pragma unroll
                for (int mt = 0; mt < 4; ++mt)
                    #pragma unroll
                    for (int nt = 0; nt < 4; ++nt)
                        #pragma unroll
                        for (int r = 0; r < 4; ++r) {
                            int d = 16 * q16 + 4 * r + mt;   // 4*m_loc+mt
                            int eo = ebase + nt;
                            float v = acc[mt][nt][r];
                            if (ww == 0) red[d * 32 + eo] = v;
                            else         red[d * 32 + eo] += v;
                        }
            }
        }
        __syncthreads();
        // write this e-half: red[d][eo] -> slot[d*64 + h*32 + eo]
        #pragma unroll
        for (int q = 0; q < 2; ++q) {
            int f = q * 1024 + t * 4;      // 0..2047
            int d = f >> 5, eo = f & 31;
            *(float4*)&slot[d * Dn + h * 32 + eo] = *(const float4*)&red[f];
        }
    }
    if (t < Dn)
        slot[Dn * Dn + t] = ksr[t] + ksr[Dn + t] + ksr[2 * Dn + t] + ksr[3 * Dn + t];
}

// ---------------- Reduce chunk-partials -> final slot layout [head][4096 kv + 64 ksum] ----------------
__global__ __launch_bounds__(256) void reduce_partials(const float* __restrict__ part,
                                                       float* __restrict__ slots,
                                                       int nchunks) {
    const int head = blockIdx.x;
    const int idx = blockIdx.y * 256 + threadIdx.x;
    if (idx >= SLOT) return;
    float s = 0.f;
    for (int c = 0; c < nchunks; ++c)
        s += part[((size_t)c * NHEAD + head) * SLOT + idx];
    slots[(size_t)head * SLOT + idx] = s;
}

// ---------------- Pass 2: out = (Q / (Q.ksum + eps)) @ kv ----------------
__global__ __launch_bounds__(256) void pass2(const float* __restrict__ Q,
                                             const float* __restrict__ slots,
                                             float* __restrict__ out) {
    const int head = blockIdx.x;
    const int rc = blockIdx.y;  // 64-row chunk
    const int t = threadIdx.x;
    const int ti = t >> 4, tj = t & 15;
    const int r0 = ti * 4, e0 = tj * 4;   // 4 rows x 4 cols per thread

    __shared__ float kvs[Dn][Dn];
    __shared__ float qT[Dn][68];          // transposed Q tile, padded
    __shared__ float kss[Dn];

    const float* kvh = slots + (size_t)head * SLOT;

    // stage kv (16KB; L2/L3-resident after reduce)
    const float4* kvsrc = (const float4*)kvh;
    float4* kvdst = (float4*)&kvs[0][0];
    #pragma unroll
    for (int kk = 0; kk < 4; ++kk) kvdst[t + 256 * kk] = kvsrc[t + 256 * kk];
    if (t < 16) ((float4*)kss)[t] = ((const float4*)(kvh + Dn * Dn))[t];

    // stage Q tile transposed: qT[d][row]
    const float4* Qsrc = (const float4*)(Q + ((size_t)head * Sn + (size_t)rc * 64) * Dn);
    #pragma unroll
    for (int kk = 0; kk < 4; ++kk) {
        int f = t + 256 * kk;
        int row = f >> 4, d4 = (f & 15) * 4;
        float4 q4 = Qsrc[f];
        qT[d4 + 0][row] = q4.x;
        qT[d4 + 1][row] = q4.y;
        qT[d4 + 2][row] = q4.z;
        qT[d4 + 3][row] = q4.w;
    }
    __syncthreads();

    float acc[4][4] = {};
    float dn[4] = {0.f, 0.f, 0.f, 0.f};
    #pragma unroll 8
    for (int d = 0; d < Dn; ++d) {
        float4 a = *(const float4*)&qT[d][r0];     // q for 4 rows at dim d
        float4 b = *(const float4*)&kvs[d][e0];    // kv row d, 4 cols
        float ksd = kss[d];
        float av[4] = {a.x, a.y, a.z, a.w};
        float bv[4] = {b.x, b.y, b.z, b.w};
        #pragma unroll
        for (int i = 0; i < 4; ++i) {
            dn[i] += av[i] * ksd;
            #pragma unroll
            for (int j = 0; j < 4; ++j) acc[i][j] += av[i] * bv[j];
        }
    }

    float* Oh = out + ((size_t)head * Sn + (size_t)rc * 64) * Dn;
    #pragma unroll
    for (int i = 0; i < 4; ++i) {
        float inv = 1.0f / (dn[i] + FEPS);
        float4 r;
        r.x = acc[i][0] * inv; r.y = acc[i][1] * inv;
        r.z = acc[i][2] * inv; r.w = acc[i][3] * inv;
        *(float4*)&Oh[(size_t)(r0 + i) * Dn + e0] = r;
    }
}

extern "C" void kernel_launch(void* const* d_in, const int* in_sizes, int n_in,
                              void* d_out, int out_size, void* d_ws, size_t ws_size,
                              hipStream_t stream) {
    (void)in_sizes; (void)n_in; (void)out_size;
    const float* Q = (const float*)d_in[0];
    const float* K = (const float*)d_in[1];
    const float* V = (const float*)d_in[2];
    float* out = (float*)d_out;

    float* slots = (float*)d_ws;                         // [64][4160] final kv+ksum

    // pick the largest chunk count whose partial buffer fits in d_ws
    int chunks = 1;
    const int cand[4] = {16, 8, 4, 2};
    for (int ci = 0; ci < 4; ++ci) {
        if ((size_t)(1 + cand[ci]) * NHEAD * SLOT * sizeof(float) <= ws_size) {
            chunks = cand[ci];
            break;
        }
    }

    if (chunks > 1) {
        float* part = slots + (size_t)NHEAD * SLOT;      // [chunks][64][4160]
        hipLaunchKernelGGL(pass1, dim3(NHEAD, chunks), dim3(256), 0, stream,
                           K, V, part, Sn / chunks);
        hipLaunchKernelGGL(reduce_partials, dim3(NHEAD, (SLOT + 255) / 256), dim3(256), 0, stream,
                           part, slots, chunks);
    } else {
        // one block per head writes the final slot directly (no reduce needed)
        hipLaunchKernelGGL(pass1, dim3(NHEAD, 1), dim3(256), 0, stream,
                           K, V, slots, Sn);
    }
    hipLaunchKernelGGL(pass2, dim3(NHEAD, Sn / 64), dim3(256), 0, stream,
                       Q, slots, out);
}